// Round 6
// baseline (1307.601 us; speedup 1.0000x reference)
//
#include <hip/hip_runtime.h>
#include <math.h>

#define FLAT   8192
#define NB     64
#define OD_    80
#define NE_    512
#define EATT_  4096
#define MAXACT 4096
// per-node partial slot layout in acc_glob (544 floats/node):
//   chunks 0..11 (A,B): base c*32, 32 slots  -> out_s contributions
//   chunks 12..15 (C) : base 384+(c-12)*16   -> q (scalar coeff for yv)
//   chunks 16..17 (D) : base 448+(c-16)*48, layout comp*16+o -> out_v direct
#define ACCW 544

__device__ __forceinline__ float silu_f(float x) { return x / (1.f + __expf(-x)); }
__device__ __forceinline__ float sigm_f(float x) { return 1.f / (1.f + __expf(-x)); }

// ---------------- init ----------------
__global__ void k_init(float* vabs, int* widx, int* count) {
  int t = blockIdx.x * 256 + threadIdx.x;
  if (t < FLAT) widx[t] = -1;
  if (t < NB * OD_) vabs[t] = 0.f;
  if (t == 0) *count = 0;
}

// ---------------- scatter: last-write-wins == max edge index ----------------
__global__ void k_scatter(const int* __restrict__ att_dst, int* widx) {
  int i = blockIdx.x * 256 + threadIdx.x;
  if (i < EATT_) atomicMax(&widx[att_dst[i]], i);
}

// ---------------- compact active-node list ----------------
__global__ void k_build(const int* __restrict__ widx, int* active, int* count) {
  int j = blockIdx.x * 256 + threadIdx.x;
  if (j < FLAT && widx[j] >= 0) {
    int p = atomicAdd(count, 1);
    active[p] = j;
  }
}

// ---------------- per active node: rbf, hidden a(128), gate, env, coefs ----------------
__global__ void k_node(const int* __restrict__ count, const int* __restrict__ active,
                       const int* __restrict__ widx,
                       const float* __restrict__ att_dist, const float* __restrict__ att_vec,
                       const int* __restrict__ z, const float* __restrict__ w_zemb,
                       const int* __restrict__ abs_idx,
                       const float* __restrict__ w1_rad, const float* __restrict__ b1_rad,
                       const float* __restrict__ h,
                       const float* __restrict__ wg1, const float* __restrict__ bg1,
                       const float* __restrict__ wg2, const float* __restrict__ bg2,
                       const float* __restrict__ h_full,
                       float* a_glob, float* coef_glob, float* meta_f, int* meta_b) {
  int pos = blockIdx.x;
  if (pos >= *count) return;
  int t = threadIdx.x;  // 128 threads
  __shared__ float win[49];
  __shared__ float yv_s[3];
  __shared__ float red[128];
  __shared__ float sh_d;

  int j = active[pos];
  int b = j >> 7;
  int n = j & 127;
  int e = widx[j];

  if (t == 0) {
    float d = att_dist[e];
    sh_d = d;
    float eps = fmaxf(d, 1e-8f);
    const float s3 = 1.7320508075688772f;
    yv_s[0] = s3 * att_vec[e * 3 + 0] / eps;
    yv_s[1] = s3 * att_vec[e * 3 + 1] / eps;
    yv_s[2] = s3 * att_vec[e * 3 + 2] / eps;
  }
  int nabs = abs_idx[b];
  float isab = (n == nabs) ? 1.f : 0.f;
  if (t < 32) win[t] = w_zemb[z[j] * 32 + t];
  if (t == 32) win[32] = isab;
  if (t >= 33 && t < 49) {
    int k = t - 33;
    float d = att_dist[e];
    float x = (d - (float)k * (1.f / 3.f)) * 3.f;  // width = CUTOFF/(RBF-1) = 1/3
    win[t] = __expf(-0.5f * x * x);
  }
  __syncthreads();

  // hidden a = silu(win @ w1_rad + b1_rad)   (49 -> 128)
  {
    float s = b1_rad[t];
    for (int k = 0; k < 49; ++k) s = fmaf(win[k], w1_rad[k * 128 + t], s);
    a_glob[pos * 128 + t] = silu_f(s);
  }

  // gate MLP hidden (273 -> 128)
  {
    float g = bg1[t];
    const float* habs = h + (size_t)(b * 128 + nabs) * 128;
    const float* hn   = h + (size_t)j * 128;
    for (int c = 0; c < 128; ++c) g = fmaf(habs[c], wg1[c * 128 + t], g);
    for (int c = 0; c < 128; ++c) g = fmaf(hn[c],   wg1[(128 + c) * 128 + t], g);
    for (int k = 0; k < 16; ++k)  g = fmaf(win[33 + k], wg1[(256 + k) * 128 + t], g);
    g = fmaf(isab, wg1[272 * 128 + t], g);
    red[t] = silu_f(g) * wg2[t];
  }
  __syncthreads();

  // per-node contraction coefficients: [s1(64), p*inv_s3(32), v1(96)]
  const float* hf = h_full + (size_t)j * 160;
  if (t < 64) coef_glob[pos * 192 + t] = hf[t];
  if (t >= 64 && t < 96) {
    int i = t - 64;
    float pv = hf[64 + i * 3 + 0] * yv_s[0] + hf[64 + i * 3 + 1] * yv_s[1] +
               hf[64 + i * 3 + 2] * yv_s[2];
    coef_glob[pos * 192 + t] = pv * 0.5773502691896258f;
  }
  if (t < 96) coef_glob[pos * 192 + 96 + t] = hf[64 + t];

  if (t == 0) {
    float tot = 0.f;
    for (int k = 0; k < 128; ++k) tot += red[k];
    tot += bg2[0];
    float gate = sigm_f(tot);
    float d = sh_d;
    float env = (d < 5.f) ? 0.5f * (__cosf(3.14159265358979323846f * d * 0.2f) + 1.f) : 0.f;
    meta_f[pos * 4 + 0] = yv_s[0];
    meta_f[pos * 4 + 1] = yv_s[1];
    meta_f[pos * 4 + 2] = yv_s[2];
    meta_f[pos * 4 + 3] = gate * env;
    meta_b[pos] = b;
  }
}

// ---------------- radial GEMM + fused contraction (LDS double-buffered) ----------------
// grid (18 col-chunks x 64 node-tiles). Block tile: 64 nodes x 256 cols, K=128,
// BK=16 double-buffered in LDS.
// Round-5 lessons: (1) __launch_bounds__ 2nd arg is only a FLOOR; the scheduler
// targets 6 waves/EU (84 VGPR) and spilled acc -> 2.8 GB HBM. amdgpu_waves_per_eu(3,3)
// caps the target -> ~170 VGPR budget. (2) per-thread cols tx*16+j gave 8-way
// bank conflicts on every ds_read_b128 (2.3e7 conflicts); cols are now
// 64q + 4tx + e so each read is 256 contiguous bytes across 16 lanes (free).
__global__ __launch_bounds__(256)
__attribute__((amdgpu_waves_per_eu(3, 3)))
void k_rgemm(const int* __restrict__ count,
             const float* __restrict__ a_glob,
             const float* __restrict__ coef_glob,
             const float* __restrict__ w2,
             const float* __restrict__ b2,
             float* __restrict__ acc_glob) {
  int c = blockIdx.x;          // 0..17
  int nbase = blockIdx.y * 64;
  if (nbase >= *count) return;
  int t = threadIdx.x;
  int tx = t & 15, ty = t >> 4;
  int n0 = ty * 4;

  __shared__ float w_s[2][16][256];  // 32 KB
  __shared__ float a_s[2][16][64];   // 8 KB  (transposed: [k][node])

  const float* wbase = w2 + c * 256;
  int wkr = t >> 6;            // 0..3   (k-row of this thread's float4, +4 per it)
  int wc4 = t & 63;            // col/4
  int anode = t >> 2, aq = t & 3;
  const float* aptr = a_glob + (size_t)(nbase + anode) * 128 + aq * 4;

  float4 wpre[4];
  float4 apre;
  // prefetch + store tile 0
#pragma unroll
  for (int it = 0; it < 4; ++it)
    wpre[it] = *(const float4*)(wbase + (size_t)(it * 4 + wkr) * 4608 + wc4 * 4);
  apre = *(const float4*)aptr;
#pragma unroll
  for (int it = 0; it < 4; ++it)
    *(float4*)&w_s[0][it * 4 + wkr][wc4 * 4] = wpre[it];
  a_s[0][aq * 4 + 0][anode] = apre.x;
  a_s[0][aq * 4 + 1][anode] = apre.y;
  a_s[0][aq * 4 + 2][anode] = apre.z;
  a_s[0][aq * 4 + 3][anode] = apre.w;
  __syncthreads();

  // acc[i][j]: node row i (n0+i), col j = 4q+e  <->  global col c*256 + 64q + 4tx + e
  float acc[4][16];
#pragma unroll
  for (int i = 0; i < 4; ++i)
#pragma unroll
    for (int j = 0; j < 16; ++j) acc[i][j] = 0.f;

#define FMA_ROW(i, ax)                                   \
  acc[i][0]  = fmaf(ax, w0.x,  acc[i][0]);               \
  acc[i][1]  = fmaf(ax, w0.y,  acc[i][1]);               \
  acc[i][2]  = fmaf(ax, w0.z,  acc[i][2]);               \
  acc[i][3]  = fmaf(ax, w0.w,  acc[i][3]);               \
  acc[i][4]  = fmaf(ax, w1v.x, acc[i][4]);               \
  acc[i][5]  = fmaf(ax, w1v.y, acc[i][5]);               \
  acc[i][6]  = fmaf(ax, w1v.z, acc[i][6]);               \
  acc[i][7]  = fmaf(ax, w1v.w, acc[i][7]);               \
  acc[i][8]  = fmaf(ax, w2v.x, acc[i][8]);               \
  acc[i][9]  = fmaf(ax, w2v.y, acc[i][9]);               \
  acc[i][10] = fmaf(ax, w2v.z, acc[i][10]);              \
  acc[i][11] = fmaf(ax, w2v.w, acc[i][11]);              \
  acc[i][12] = fmaf(ax, w3v.x, acc[i][12]);              \
  acc[i][13] = fmaf(ax, w3v.y, acc[i][13]);              \
  acc[i][14] = fmaf(ax, w3v.z, acc[i][14]);              \
  acc[i][15] = fmaf(ax, w3v.w, acc[i][15]);

  for (int kb = 0; kb < 8; ++kb) {
    int cur = kb & 1;
    if (kb < 7) {
#pragma unroll
      for (int it = 0; it < 4; ++it)
        wpre[it] = *(const float4*)(wbase + (size_t)((kb + 1) * 16 + it * 4 + wkr) * 4608 + wc4 * 4);
      apre = *(const float4*)(aptr + (kb + 1) * 16);
    }
#pragma unroll
    for (int k = 0; k < 16; ++k) {
      float4 av  = *(const float4*)&a_s[cur][k][n0];
      float4 w0  = *(const float4*)&w_s[cur][k][0   + tx * 4];
      float4 w1v = *(const float4*)&w_s[cur][k][64  + tx * 4];
      float4 w2v = *(const float4*)&w_s[cur][k][128 + tx * 4];
      float4 w3v = *(const float4*)&w_s[cur][k][192 + tx * 4];
      FMA_ROW(0, av.x)
      FMA_ROW(1, av.y)
      FMA_ROW(2, av.z)
      FMA_ROW(3, av.w)
    }
    if (kb < 7) {
      int nxt = cur ^ 1;
#pragma unroll
      for (int it = 0; it < 4; ++it)
        *(float4*)&w_s[nxt][it * 4 + wkr][wc4 * 4] = wpre[it];
      a_s[nxt][aq * 4 + 0][anode] = apre.x;
      a_s[nxt][aq * 4 + 1][anode] = apre.y;
      a_s[nxt][aq * 4 + 2][anode] = apre.z;
      a_s[nxt][aq * 4 + 3][anode] = apre.w;
    }
    __syncthreads();
  }
#undef FMA_ROW

  // + bias (tpw = a@w2 + b2); j = 4q+e -> col = c*256 + 64q + 4tx + e
  {
    const float* bp = b2 + c * 256 + tx * 4;
    float4 bq0 = *(const float4*)(bp + 0);
    float4 bq1 = *(const float4*)(bp + 64);
    float4 bq2 = *(const float4*)(bp + 128);
    float4 bq3 = *(const float4*)(bp + 192);
#pragma unroll
    for (int i = 0; i < 4; ++i) {
      acc[i][0] += bq0.x;  acc[i][1] += bq0.y;  acc[i][2] += bq0.z;  acc[i][3] += bq0.w;
      acc[i][4] += bq1.x;  acc[i][5] += bq1.y;  acc[i][6] += bq1.z;  acc[i][7] += bq1.w;
      acc[i][8] += bq2.x;  acc[i][9] += bq2.y;  acc[i][10] += bq2.z; acc[i][11] += bq2.w;
      acc[i][12] += bq3.x; acc[i][13] += bq3.y; acc[i][14] += bq3.z; acc[i][15] += bq3.w;
    }
  }

  if (c < 12) {
    // A/B: i_loc = 2q + (tx>>3), o = 4(tx&7)+e. coef idx = c*8 + i_loc.
    int hb = tx >> 3;
    int ostore = 4 * (tx & 7);
#pragma unroll
    for (int i = 0; i < 4; ++i) {
      const float* cfp = coef_glob + (size_t)(nbase + n0 + i) * 192 + c * 8 + hb;
      float cf0 = cfp[0], cf1 = cfp[2], cf2 = cfp[4], cf3 = cfp[6];
      float ve[4];
#pragma unroll
      for (int e = 0; e < 4; ++e) {
        float v = acc[i][e] * cf0 + acc[i][4 + e] * cf1 +
                  acc[i][8 + e] * cf2 + acc[i][12 + e] * cf3;
        v += __shfl_xor(v, 8);
        ve[e] = v;
      }
      if (tx < 8)
        *(float4*)&acc_glob[(size_t)(nbase + n0 + i) * ACCW + c * 32 + ostore] =
            make_float4(ve[0], ve[1], ve[2], ve[3]);
    }
  } else if (c < 16) {
    // C: i_loc = 4q + (tx>>2), o = 4(tx&3)+e. coef = s1[(c-12)*16 + i_loc].
    int qb = tx >> 2;
    int ostore = 4 * (tx & 3);
#pragma unroll
    for (int i = 0; i < 4; ++i) {
      const float* cfp = coef_glob + (size_t)(nbase + n0 + i) * 192 + (c - 12) * 16 + qb;
      float cf0 = cfp[0], cf1 = cfp[4], cf2 = cfp[8], cf3 = cfp[12];
      float ve[4];
#pragma unroll
      for (int e = 0; e < 4; ++e) {
        float v = acc[i][e] * cf0 + acc[i][4 + e] * cf1 +
                  acc[i][8 + e] * cf2 + acc[i][12 + e] * cf3;
        v += __shfl_xor(v, 4);
        v += __shfl_xor(v, 8);
        ve[e] = v;
      }
      if (tx < 4)
        *(float4*)&acc_glob[(size_t)(nbase + n0 + i) * ACCW + 384 + (c - 12) * 16 + ostore] =
            make_float4(ve[0], ve[1], ve[2], ve[3]);
    }
  } else {
    // D: i_loc = 4q + (tx>>2), o = 4(tx&3)+e; v1 3-vector coefs; layout comp*16+o.
    int qb = tx >> 2;
    int ostore = 4 * (tx & 3);
#pragma unroll
    for (int i = 0; i < 4; ++i) {
      const float* cfp = coef_glob + (size_t)(nbase + n0 + i) * 192 + 96 +
                         ((size_t)(c - 16) * 16 + qb) * 3;
#pragma unroll
      for (int comp = 0; comp < 3; ++comp) {
        float cf0 = cfp[comp], cf1 = cfp[12 + comp], cf2 = cfp[24 + comp], cf3 = cfp[36 + comp];
        float ve[4];
#pragma unroll
        for (int e = 0; e < 4; ++e) {
          float v = acc[i][e] * cf0 + acc[i][4 + e] * cf1 +
                    acc[i][8 + e] * cf2 + acc[i][12 + e] * cf3;
          v += __shfl_xor(v, 4);
          v += __shfl_xor(v, 8);
          ve[e] = v;
        }
        if (tx < 4)
          *(float4*)&acc_glob[(size_t)(nbase + n0 + i) * ACCW + 448 + (c - 16) * 48 +
                              comp * 16 + ostore] = make_float4(ve[0], ve[1], ve[2], ve[3]);
      }
    }
  }
}

// ---------------- reduce 544 partials/node -> v_abs[b][80] ----------------
__global__ void k_combine(const int* __restrict__ count, const float* __restrict__ acc_glob,
                          const float* __restrict__ meta_f, const int* __restrict__ meta_b,
                          float* vabs) {
  int g = blockIdx.x * 256 + threadIdx.x;
  int pos = g / 96, slot = g - pos * 96;
  if (pos >= *count) return;
  const float* acc = acc_glob + (size_t)pos * ACCW;
  float sc = meta_f[pos * 4 + 3] * 0.10206207261596577f;  // gate*env / sqrt(96)
  float* vb = vabs + meta_b[pos] * 80;
  if (slot < 32) {
    float s = 0.f;
#pragma unroll
    for (int cc = 0; cc < 12; ++cc) s += acc[cc * 32 + slot];
    atomicAdd(&vb[slot], s * sc);
  } else if (slot < 48) {
    int o = slot - 32;
    float q = acc[384 + o] + acc[384 + 16 + o] + acc[384 + 32 + o] + acc[384 + 48 + o];
    q *= sc;
    atomicAdd(&vb[32 + o * 3 + 0], q * meta_f[pos * 4 + 0]);
    atomicAdd(&vb[32 + o * 3 + 1], q * meta_f[pos * 4 + 1]);
    atomicAdd(&vb[32 + o * 3 + 2], q * meta_f[pos * 4 + 2]);
  } else {
    int s2 = slot - 48;         // s2 = o*3 + comp in output layout
    int o = s2 / 3, comp = s2 - o * 3;
    float dsum = acc[448 + comp * 16 + o] + acc[496 + comp * 16 + o];
    atomicAdd(&vb[32 + s2], dsum * sc);
  }
}

// ---------------- edge-feature scales -> scale_full[512][80] ----------------
__global__ void k_scales(const float* __restrict__ e_feat,
                         const float* __restrict__ we1, const float* __restrict__ be1,
                         const float* __restrict__ we2, const float* __restrict__ be2,
                         float* sfull) {
  int row = blockIdx.x;  // 512
  int t = threadIdx.x;   // 128
  __shared__ float hid[128];
  const float* ef = e_feat + row * 16;
  float s = be1[t];
  for (int k = 0; k < 16; ++k) s = fmaf(ef[k], we1[k * 128 + t], s);
  hid[t] = silu_f(s);
  __syncthreads();
  if (t < 48) {
    float o = be2[t];
    for (int k = 0; k < 128; ++k) o = fmaf(hid[k], we2[k * 48 + t], o);
    if (t < 32) sfull[row * 80 + t] = o;
    else {
      int oo = t - 32;
      sfull[row * 80 + 32 + oo * 3 + 0] = o;
      sfull[row * 80 + 32 + oo * 3 + 1] = o;
      sfull[row * 80 + 32 + oo * 3 + 2] = o;
    }
  }
}

// ---------------- head MLP: 32 rows/block, transposed LDS activations ----------------
__global__ __launch_bounds__(256) void k_head(const float* __restrict__ vabs,
                                              const float* __restrict__ sfull,
                                              const float* __restrict__ wo1, const float* __restrict__ bo1,
                                              const float* __restrict__ wo2, const float* __restrict__ bo2,
                                              const float* __restrict__ wo3, const float* __restrict__ bo3,
                                              float* __restrict__ out) {
  int blk = blockIdx.x;  // 1024 = 64 b x 16 e-tiles
  int b = blk >> 4;
  int e0 = (blk & 15) * 32;
  int t = threadIdx.x;

  __shared__ float va[80];
  __shared__ float smem[2592 + 4608 + 4608];  // sfl | x1_t | x2_t(alias inv_t)
  float* sfl  = smem;            // [32][81]
  float* x1t  = smem + 2592;     // [128][36]
  float* x2t  = smem + 7200;     // [128][36]
  float* invt = x2t;             // [48][36], dead before x2t written

  if (t < 80) va[t] = vabs[b * 80 + t];
  for (int idx = t; idx < 32 * 80; idx += 256) {
    int r = idx / 80, cc = idx - r * 80;
    sfl[r * 81 + cc] = sfull[e0 * 80 + idx];
  }
  __syncthreads();

  // inv (transposed [c][r], stride 36)
  for (int idx = t; idx < 48 * 32; idx += 256) {
    int cd = idx >> 5, r = idx & 31;
    float v;
    if (cd < 32) v = va[cd] * sfl[r * 81 + cd];
    else {
      int base = 32 + (cd - 32) * 3;
      float m0 = va[base + 0] * sfl[r * 81 + base + 0];
      float m1 = va[base + 1] * sfl[r * 81 + base + 1];
      float m2 = va[base + 2] * sfl[r * 81 + base + 2];
      v = sqrtf(m0 * m0 + m1 * m1 + m2 * m2 + 1e-12f);
    }
    invt[cd * 36 + r] = v;
  }
  __syncthreads();

  // L1: 48 -> 128, thread = (col, half-rows), 16 rows in registers
  {
    int col = t & 127, r0 = (t >> 7) * 16;
    float a[16];
    float bb = bo1[col];
#pragma unroll
    for (int r = 0; r < 16; ++r) a[r] = bb;
    for (int k = 0; k < 48; ++k) {
      float w = wo1[k * 128 + col];
      const float* xp = &invt[k * 36 + r0];
      float4 x0 = *(const float4*)(xp + 0);
      float4 x1 = *(const float4*)(xp + 4);
      float4 x2 = *(const float4*)(xp + 8);
      float4 x3 = *(const float4*)(xp + 12);
      float xs[16] = {x0.x, x0.y, x0.z, x0.w, x1.x, x1.y, x1.z, x1.w,
                      x2.x, x2.y, x2.z, x2.w, x3.x, x3.y, x3.z, x3.w};
#pragma unroll
      for (int r = 0; r < 16; ++r) a[r] = fmaf(xs[r], w, a[r]);
    }
#pragma unroll
    for (int r = 0; r < 16; ++r) x1t[col * 36 + r0 + r] = silu_f(a[r]);
  }
  __syncthreads();

  // L2: 128 -> 128
  {
    int col = t & 127, r0 = (t >> 7) * 16;
    float a[16];
    float bb = bo2[col];
#pragma unroll
    for (int r = 0; r < 16; ++r) a[r] = bb;
    for (int k = 0; k < 128; ++k) {
      float w = wo2[k * 128 + col];
      const float* xp = &x1t[k * 36 + r0];
      float4 x0 = *(const float4*)(xp + 0);
      float4 x1 = *(const float4*)(xp + 4);
      float4 x2 = *(const float4*)(xp + 8);
      float4 x3 = *(const float4*)(xp + 12);
      float xs[16] = {x0.x, x0.y, x0.z, x0.w, x1.x, x1.y, x1.z, x1.w,
                      x2.x, x2.y, x2.z, x2.w, x3.x, x3.y, x3.z, x3.w};
#pragma unroll
      for (int r = 0; r < 16; ++r) a[r] = fmaf(xs[r], w, a[r]);
    }
#pragma unroll
    for (int r = 0; r < 16; ++r) x2t[col * 36 + r0 + r] = silu_f(a[r]);
  }
  __syncthreads();

  // L3: 128 -> 256, thread = col, all 32 rows in registers
  {
    int col = t;
    float a[32];
    float bb = bo3[col];
#pragma unroll
    for (int r = 0; r < 32; ++r) a[r] = bb;
    for (int k = 0; k < 128; ++k) {
      float w = wo3[k * 256 + col];
      const float* xp = &x2t[k * 36];
#pragma unroll
      for (int q = 0; q < 8; ++q) {
        float4 xv = *(const float4*)(xp + q * 4);
        a[q * 4 + 0] = fmaf(xv.x, w, a[q * 4 + 0]);
        a[q * 4 + 1] = fmaf(xv.y, w, a[q * 4 + 1]);
        a[q * 4 + 2] = fmaf(xv.z, w, a[q * 4 + 2]);
        a[q * 4 + 3] = fmaf(xv.w, w, a[q * 4 + 3]);
      }
    }
    float* op = out + ((size_t)(b * 512 + e0)) * 256 + col;
#pragma unroll
    for (int r = 0; r < 32; ++r) op[(size_t)r * 256] = a[r];
  }
}

extern "C" void kernel_launch(void* const* d_in, const int* in_sizes, int n_in,
                              void* d_out, int out_size, void* d_ws, size_t ws_size,
                              hipStream_t stream) {
  const float* h        = (const float*)d_in[0];
  const float* h_full   = (const float*)d_in[1];
  const int*   z        = (const int*)d_in[2];
  const float* e_feat   = (const float*)d_in[4];
  const int*   abs_idx  = (const int*)d_in[5];
  const int*   att_dst  = (const int*)d_in[6];
  const float* att_dist = (const float*)d_in[7];
  const float* att_vec  = (const float*)d_in[8];
  const float* w_zemb   = (const float*)d_in[9];
  const float* w1_rad   = (const float*)d_in[10];
  const float* b1_rad   = (const float*)d_in[11];
  const float* w2_rad   = (const float*)d_in[12];
  const float* b2_rad   = (const float*)d_in[13];
  const float* wg1      = (const float*)d_in[14];
  const float* bg1      = (const float*)d_in[15];
  const float* wg2      = (const float*)d_in[16];
  const float* bg2      = (const float*)d_in[17];
  const float* we1      = (const float*)d_in[18];
  const float* be1      = (const float*)d_in[19];
  const float* we2      = (const float*)d_in[20];
  const float* be2      = (const float*)d_in[21];
  const float* wo1      = (const float*)d_in[22];
  const float* bo1      = (const float*)d_in[23];
  const float* wo2      = (const float*)d_in[24];
  const float* bo2      = (const float*)d_in[25];
  const float* wo3      = (const float*)d_in[26];
  const float* bo3      = (const float*)d_in[27];
  float* out = (float*)d_out;

  // workspace layout (~14.3 MB)
  float* a_glob    = (float*)d_ws;                   // MAXACT*128
  float* coef_glob = a_glob + MAXACT * 128;          // MAXACT*192
  float* acc_glob  = coef_glob + MAXACT * 192;       // MAXACT*544
  float* meta_f    = acc_glob + (size_t)MAXACT * ACCW;  // MAXACT*4
  float* vabs      = meta_f + MAXACT * 4;            // 64*80
  float* sfull     = vabs + NB * OD_;                // 512*80
  int* widx   = (int*)(sfull + NE_ * OD_);           // 8192
  int* active = widx + FLAT;                         // 4096
  int* meta_b = active + MAXACT;                     // 4096
  int* count  = meta_b + MAXACT;                     // 1

  k_init<<<32, 256, 0, stream>>>(vabs, widx, count);
  k_scatter<<<16, 256, 0, stream>>>(att_dst, widx);
  k_build<<<32, 256, 0, stream>>>(widx, active, count);
  k_node<<<MAXACT, 128, 0, stream>>>(count, active, widx, att_dist, att_vec, z, w_zemb,
                                     abs_idx, w1_rad, b1_rad, h, wg1, bg1, wg2, bg2,
                                     h_full, a_glob, coef_glob, meta_f, meta_b);
  k_rgemm<<<dim3(18, 64), 256, 0, stream>>>(count, a_glob, coef_glob, w2_rad, b2_rad,
                                            acc_glob);
  k_combine<<<1536, 256, 0, stream>>>(count, acc_glob, meta_f, meta_b, vabs);
  k_scales<<<512, 128, 0, stream>>>(e_feat, we1, be1, we2, be2, sfull);
  k_head<<<1024, 256, 0, stream>>>(vabs, sfull, wo1, bo1, wo2, bo2, wo3, bo3, out);
}

// Round 7
// 316.485 us; speedup vs baseline: 4.1316x; 4.1316x over previous
//
#include <hip/hip_runtime.h>
#include <math.h>

#define FLAT   8192
#define NB     64
#define OD_    80
#define NE_    512
#define EATT_  4096
#define MAXACT 4096
// acc_glob: 96 floats/node, atomically accumulated by k_rgemm:
//   [0..31]  out_s partial (pre gate/env/norm)
//   [32..47] q (scalar coeff that multiplies yv)
//   [48..95] D-term out_v, layout comp*16 + o
#define ACCW 96

__device__ __forceinline__ float silu_f(float x) { return x / (1.f + __expf(-x)); }
__device__ __forceinline__ float sigm_f(float x) { return 1.f / (1.f + __expf(-x)); }

// ---------------- init: zero acc + vabs, widx=-1, count=0 ----------------
__global__ void k_init(float* acc, float* vabs, int* widx, int* count) {
  int t = blockIdx.x * 256 + threadIdx.x;
  if (t < MAXACT * ACCW) acc[t] = 0.f;
  if (t < FLAT) widx[t] = -1;
  if (t < NB * OD_) vabs[t] = 0.f;
  if (t == 0) *count = 0;
}

// ---------------- scatter: last-write-wins == max edge index ----------------
__global__ void k_scatter(const int* __restrict__ att_dst, int* widx) {
  int i = blockIdx.x * 256 + threadIdx.x;
  if (i < EATT_) atomicMax(&widx[att_dst[i]], i);
}

// ---------------- compact active-node list ----------------
__global__ void k_build(const int* __restrict__ widx, int* active, int* count) {
  int j = blockIdx.x * 256 + threadIdx.x;
  if (j < FLAT && widx[j] >= 0) {
    int p = atomicAdd(count, 1);
    active[p] = j;
  }
}

// ---------------- per active node: rbf, hidden a(128), gate, env, coefs ----------------
__global__ void k_node(const int* __restrict__ count, const int* __restrict__ active,
                       const int* __restrict__ widx,
                       const float* __restrict__ att_dist, const float* __restrict__ att_vec,
                       const int* __restrict__ z, const float* __restrict__ w_zemb,
                       const int* __restrict__ abs_idx,
                       const float* __restrict__ w1_rad, const float* __restrict__ b1_rad,
                       const float* __restrict__ h,
                       const float* __restrict__ wg1, const float* __restrict__ bg1,
                       const float* __restrict__ wg2, const float* __restrict__ bg2,
                       const float* __restrict__ h_full,
                       float* a_glob, float* coef_glob, float* meta_f, int* meta_b) {
  int pos = blockIdx.x;
  if (pos >= *count) return;
  int t = threadIdx.x;  // 128 threads
  __shared__ float win[49];
  __shared__ float yv_s[3];
  __shared__ float red[128];
  __shared__ float sh_d;

  int j = active[pos];
  int b = j >> 7;
  int n = j & 127;
  int e = widx[j];

  if (t == 0) {
    float d = att_dist[e];
    sh_d = d;
    float eps = fmaxf(d, 1e-8f);
    const float s3 = 1.7320508075688772f;
    yv_s[0] = s3 * att_vec[e * 3 + 0] / eps;
    yv_s[1] = s3 * att_vec[e * 3 + 1] / eps;
    yv_s[2] = s3 * att_vec[e * 3 + 2] / eps;
  }
  int nabs = abs_idx[b];
  float isab = (n == nabs) ? 1.f : 0.f;
  if (t < 32) win[t] = w_zemb[z[j] * 32 + t];
  if (t == 32) win[32] = isab;
  if (t >= 33 && t < 49) {
    int k = t - 33;
    float d = att_dist[e];
    float x = (d - (float)k * (1.f / 3.f)) * 3.f;  // width = CUTOFF/(RBF-1) = 1/3
    win[t] = __expf(-0.5f * x * x);
  }
  __syncthreads();

  // hidden a = silu(win @ w1_rad + b1_rad)   (49 -> 128)
  {
    float s = b1_rad[t];
    for (int k = 0; k < 49; ++k) s = fmaf(win[k], w1_rad[k * 128 + t], s);
    a_glob[pos * 128 + t] = silu_f(s);
  }

  // gate MLP hidden (273 -> 128)
  {
    float g = bg1[t];
    const float* habs = h + (size_t)(b * 128 + nabs) * 128;
    const float* hn   = h + (size_t)j * 128;
    for (int c = 0; c < 128; ++c) g = fmaf(habs[c], wg1[c * 128 + t], g);
    for (int c = 0; c < 128; ++c) g = fmaf(hn[c],   wg1[(128 + c) * 128 + t], g);
    for (int k = 0; k < 16; ++k)  g = fmaf(win[33 + k], wg1[(256 + k) * 128 + t], g);
    g = fmaf(isab, wg1[272 * 128 + t], g);
    red[t] = silu_f(g) * wg2[t];
  }
  __syncthreads();

  // per-node contraction coefficients: [s1(64), p*inv_s3(32), v1(96)]
  const float* hf = h_full + (size_t)j * 160;
  if (t < 64) coef_glob[pos * 192 + t] = hf[t];
  if (t >= 64 && t < 96) {
    int i = t - 64;
    float pv = hf[64 + i * 3 + 0] * yv_s[0] + hf[64 + i * 3 + 1] * yv_s[1] +
               hf[64 + i * 3 + 2] * yv_s[2];
    coef_glob[pos * 192 + t] = pv * 0.5773502691896258f;
  }
  if (t < 96) coef_glob[pos * 192 + 96 + t] = hf[64 + t];

  if (t == 0) {
    float tot = 0.f;
    for (int k = 0; k < 128; ++k) tot += red[k];
    tot += bg2[0];
    float gate = sigm_f(tot);
    float d = sh_d;
    float env = (d < 5.f) ? 0.5f * (__cosf(3.14159265358979323846f * d * 0.2f) + 1.f) : 0.f;
    meta_f[pos * 4 + 0] = yv_s[0];
    meta_f[pos * 4 + 1] = yv_s[1];
    meta_f[pos * 4 + 2] = yv_s[2];
    meta_f[pos * 4 + 3] = gate * env;
    meta_b[pos] = b;
  }
}

// ---------------- radial GEMM + fused contraction ----------------
// Rounds 2-6 lesson: the RA pins this kernel at 84 VGPR (6 waves/EU target);
// launch_bounds floor and waves_per_eu cap were both ignored -> any live set
// >84 spills into the K-loop (GBs of scratch traffic). So: fit UNDER 84.
// Block tile 64 nodes x 128 cols (grid 36 x 64), thread = 4 nodes x 8 cols
// -> 32 acc + 12 prefetch + addr ~= 60 VGPR. LDS 24 KB dbuf (6 blocks/CU).
// Thread cols: l = q*64 + tx*4 + e (2-way bank alias = free). Epilogue:
// in-register q-pair combine + shfl_xor reduce + atomicAdd into 96 slots/node.
__global__ __launch_bounds__(256) void k_rgemm(const int* __restrict__ count,
                                               const float* __restrict__ a_glob,
                                               const float* __restrict__ coef_glob,
                                               const float* __restrict__ w2,
                                               const float* __restrict__ b2,
                                               float* __restrict__ acc_glob) {
  int cc = blockIdx.x;         // 0..35 (col chunk of 128)
  int nbase = blockIdx.y * 64;
  if (nbase >= *count) return;
  int t = threadIdx.x;
  int tx = t & 15, ty = t >> 4;
  int n0 = ty * 4;

  __shared__ float w_s[2][16][128];  // 16 KB
  __shared__ float a_s[2][16][64];   // 8 KB (transposed [k][node])

  const float* wbase = w2 + cc * 128;
  int wr = t >> 5;             // 0..7; rows wr and wr+8
  int wc4 = t & 31;            // col/4
  int anode = t >> 2, aq = t & 3;
  const float* aptr = a_glob + (size_t)(nbase + anode) * 128 + aq * 4;

  float4 wpre0, wpre1, apre;
  wpre0 = *(const float4*)(wbase + (size_t)wr * 4608 + wc4 * 4);
  wpre1 = *(const float4*)(wbase + (size_t)(wr + 8) * 4608 + wc4 * 4);
  apre  = *(const float4*)aptr;
  *(float4*)&w_s[0][wr][wc4 * 4]     = wpre0;
  *(float4*)&w_s[0][wr + 8][wc4 * 4] = wpre1;
  a_s[0][aq * 4 + 0][anode] = apre.x;
  a_s[0][aq * 4 + 1][anode] = apre.y;
  a_s[0][aq * 4 + 2][anode] = apre.z;
  a_s[0][aq * 4 + 3][anode] = apre.w;
  __syncthreads();

  // acc[i][j], j = q*4+e  <->  global col cc*128 + q*64 + tx*4 + e
  float acc[4][8];
#pragma unroll
  for (int i = 0; i < 4; ++i)
#pragma unroll
    for (int j = 0; j < 8; ++j) acc[i][j] = 0.f;

  for (int kb = 0; kb < 8; ++kb) {
    int cur = kb & 1;
    if (kb < 7) {
      wpre0 = *(const float4*)(wbase + (size_t)((kb + 1) * 16 + wr) * 4608 + wc4 * 4);
      wpre1 = *(const float4*)(wbase + (size_t)((kb + 1) * 16 + wr + 8) * 4608 + wc4 * 4);
      apre  = *(const float4*)(aptr + (kb + 1) * 16);
    }
#pragma unroll
    for (int k = 0; k < 16; ++k) {
      float4 av  = *(const float4*)&a_s[cur][k][n0];
      float4 w0  = *(const float4*)&w_s[cur][k][tx * 4];
      float4 w1v = *(const float4*)&w_s[cur][k][64 + tx * 4];
#pragma unroll
      for (int i = 0; i < 4; ++i) {
        float a = (i == 0) ? av.x : (i == 1) ? av.y : (i == 2) ? av.z : av.w;
        acc[i][0] = fmaf(a, w0.x,  acc[i][0]);
        acc[i][1] = fmaf(a, w0.y,  acc[i][1]);
        acc[i][2] = fmaf(a, w0.z,  acc[i][2]);
        acc[i][3] = fmaf(a, w0.w,  acc[i][3]);
        acc[i][4] = fmaf(a, w1v.x, acc[i][4]);
        acc[i][5] = fmaf(a, w1v.y, acc[i][5]);
        acc[i][6] = fmaf(a, w1v.z, acc[i][6]);
        acc[i][7] = fmaf(a, w1v.w, acc[i][7]);
      }
    }
    if (kb < 7) {
      int nxt = cur ^ 1;
      *(float4*)&w_s[nxt][wr][wc4 * 4]     = wpre0;
      *(float4*)&w_s[nxt][wr + 8][wc4 * 4] = wpre1;
      a_s[nxt][aq * 4 + 0][anode] = apre.x;
      a_s[nxt][aq * 4 + 1][anode] = apre.y;
      a_s[nxt][aq * 4 + 2][anode] = apre.z;
      a_s[nxt][aq * 4 + 3][anode] = apre.w;
    }
    __syncthreads();
  }

  // + bias: q=0 -> b2[cc*128 + tx*4 + e], q=1 -> +64
  {
    const float* bp = b2 + cc * 128 + tx * 4;
    float4 bq0 = *(const float4*)(bp + 0);
    float4 bq1 = *(const float4*)(bp + 64);
#pragma unroll
    for (int i = 0; i < 4; ++i) {
      acc[i][0] += bq0.x; acc[i][1] += bq0.y; acc[i][2] += bq0.z; acc[i][3] += bq0.w;
      acc[i][4] += bq1.x; acc[i][5] += bq1.y; acc[i][6] += bq1.z; acc[i][7] += bq1.w;
    }
  }

  if (cc < 24) {
    // A/B region: l = q*64+tx*4+e -> i_loc = q*2+(tx>>3), o = (tx&7)*4+e.
    // coef offset = cc*4 + i_loc (A: s1 0..63; B: p 64..95 — contiguous trick).
    int txh = tx >> 3;
#pragma unroll
    for (int i = 0; i < 4; ++i) {
      const float* cfp = coef_glob + (size_t)(nbase + n0 + i) * 192 + cc * 4 + txh;
      float cf0 = cfp[0];  // q=0 (i_loc = txh)
      float cf1 = cfp[2];  // q=1 (i_loc = 2+txh)
      float* dst = acc_glob + (size_t)(nbase + n0 + i) * ACCW + (tx & 7) * 4;
#pragma unroll
      for (int e = 0; e < 4; ++e) {
        float v = acc[i][e] * cf0 + acc[i][4 + e] * cf1;
        v += __shfl_xor(v, 8);
        if (tx < 8) atomicAdd(&dst[e], v);
      }
    }
  } else if (cc < 32) {
    // C region: i = (cc-24)*8 + q*4 + (tx>>2), o = (tx&3)*4+e; s1 coefs.
    int txq = tx >> 2;
#pragma unroll
    for (int i = 0; i < 4; ++i) {
      const float* cfp = coef_glob + (size_t)(nbase + n0 + i) * 192 + (cc - 24) * 8 + txq;
      float cf0 = cfp[0];  // q=0
      float cf1 = cfp[4];  // q=1
      float* dst = acc_glob + (size_t)(nbase + n0 + i) * ACCW + 32 + (tx & 3) * 4;
#pragma unroll
      for (int e = 0; e < 4; ++e) {
        float v = acc[i][e] * cf0 + acc[i][4 + e] * cf1;
        v += __shfl_xor(v, 4);
        v += __shfl_xor(v, 8);
        if (tx < 4) atomicAdd(&dst[e], v);
      }
    }
  } else {
    // D region: i = (cc-32)*8 + q*4 + (tx>>2), o = (tx&3)*4+e; v1 3-vec coefs.
    int txq = tx >> 2;
#pragma unroll
    for (int i = 0; i < 4; ++i) {
      const float* cfp = coef_glob + (size_t)(nbase + n0 + i) * 192 + 96 +
                         ((cc - 32) * 8 + txq) * 3;
      float* dstb = acc_glob + (size_t)(nbase + n0 + i) * ACCW + 48 + (tx & 3) * 4;
#pragma unroll
      for (int comp = 0; comp < 3; ++comp) {
        float cf0 = cfp[comp];       // q=0
        float cf1 = cfp[12 + comp];  // q=1 (i+4 -> +12 floats)
#pragma unroll
        for (int e = 0; e < 4; ++e) {
          float v = acc[i][e] * cf0 + acc[i][4 + e] * cf1;
          v += __shfl_xor(v, 4);
          v += __shfl_xor(v, 8);
          if (tx < 4) atomicAdd(&dstb[comp * 16 + e], v);
        }
      }
    }
  }
}

// ---------------- combine 96 slots/node -> v_abs[b][80] ----------------
__global__ void k_combine(const int* __restrict__ count, const float* __restrict__ acc_glob,
                          const float* __restrict__ meta_f, const int* __restrict__ meta_b,
                          float* vabs) {
  int g = blockIdx.x * 256 + threadIdx.x;
  int pos = g / ACCW, slot = g - pos * ACCW;
  if (pos >= *count) return;
  const float* acc = acc_glob + (size_t)pos * ACCW;
  float sc = meta_f[pos * 4 + 3] * 0.10206207261596577f;  // gate*env / sqrt(96)
  float* vb = vabs + meta_b[pos] * 80;
  if (slot < 32) {
    atomicAdd(&vb[slot], acc[slot] * sc);
  } else if (slot < 48) {
    int o = slot - 32;
    float q = acc[slot] * sc;
    atomicAdd(&vb[32 + o * 3 + 0], q * meta_f[pos * 4 + 0]);
    atomicAdd(&vb[32 + o * 3 + 1], q * meta_f[pos * 4 + 1]);
    atomicAdd(&vb[32 + o * 3 + 2], q * meta_f[pos * 4 + 2]);
  } else {
    int s2 = slot - 48;          // comp*16 + o
    int comp = s2 >> 4, o = s2 & 15;
    atomicAdd(&vb[32 + o * 3 + comp], acc[slot] * sc);
  }
}

// ---------------- edge-feature scales -> scale_full[512][80] ----------------
__global__ void k_scales(const float* __restrict__ e_feat,
                         const float* __restrict__ we1, const float* __restrict__ be1,
                         const float* __restrict__ we2, const float* __restrict__ be2,
                         float* sfull) {
  int row = blockIdx.x;  // 512
  int t = threadIdx.x;   // 128
  __shared__ float hid[128];
  const float* ef = e_feat + row * 16;
  float s = be1[t];
  for (int k = 0; k < 16; ++k) s = fmaf(ef[k], we1[k * 128 + t], s);
  hid[t] = silu_f(s);
  __syncthreads();
  if (t < 48) {
    float o = be2[t];
    for (int k = 0; k < 128; ++k) o = fmaf(hid[k], we2[k * 48 + t], o);
    if (t < 32) sfull[row * 80 + t] = o;
    else {
      int oo = t - 32;
      sfull[row * 80 + 32 + oo * 3 + 0] = o;
      sfull[row * 80 + 32 + oo * 3 + 1] = o;
      sfull[row * 80 + 32 + oo * 3 + 2] = o;
    }
  }
}

// ---------------- head MLP: 32 rows/block, transposed LDS activations ----------------
__global__ __launch_bounds__(256) void k_head(const float* __restrict__ vabs,
                                              const float* __restrict__ sfull,
                                              const float* __restrict__ wo1, const float* __restrict__ bo1,
                                              const float* __restrict__ wo2, const float* __restrict__ bo2,
                                              const float* __restrict__ wo3, const float* __restrict__ bo3,
                                              float* __restrict__ out) {
  int blk = blockIdx.x;  // 1024 = 64 b x 16 e-tiles
  int b = blk >> 4;
  int e0 = (blk & 15) * 32;
  int t = threadIdx.x;

  __shared__ float va[80];
  __shared__ float smem[2592 + 4608 + 4608];  // sfl | x1_t | x2_t(alias inv_t)
  float* sfl  = smem;            // [32][81]
  float* x1t  = smem + 2592;     // [128][36]
  float* x2t  = smem + 7200;     // [128][36]
  float* invt = x2t;             // [48][36], dead before x2t written

  if (t < 80) va[t] = vabs[b * 80 + t];
  for (int idx = t; idx < 32 * 80; idx += 256) {
    int r = idx / 80, cc = idx - r * 80;
    sfl[r * 81 + cc] = sfull[e0 * 80 + idx];
  }
  __syncthreads();

  // inv (transposed [c][r], stride 36)
  for (int idx = t; idx < 48 * 32; idx += 256) {
    int cd = idx >> 5, r = idx & 31;
    float v;
    if (cd < 32) v = va[cd] * sfl[r * 81 + cd];
    else {
      int base = 32 + (cd - 32) * 3;
      float m0 = va[base + 0] * sfl[r * 81 + base + 0];
      float m1 = va[base + 1] * sfl[r * 81 + base + 1];
      float m2 = va[base + 2] * sfl[r * 81 + base + 2];
      v = sqrtf(m0 * m0 + m1 * m1 + m2 * m2 + 1e-12f);
    }
    invt[cd * 36 + r] = v;
  }
  __syncthreads();

  // L1: 48 -> 128, thread = (col, half-rows), 16 rows in registers
  {
    int col = t & 127, r0 = (t >> 7) * 16;
    float a[16];
    float bb = bo1[col];
#pragma unroll
    for (int r = 0; r < 16; ++r) a[r] = bb;
    for (int k = 0; k < 48; ++k) {
      float w = wo1[k * 128 + col];
      const float* xp = &invt[k * 36 + r0];
      float4 x0 = *(const float4*)(xp + 0);
      float4 x1 = *(const float4*)(xp + 4);
      float4 x2 = *(const float4*)(xp + 8);
      float4 x3 = *(const float4*)(xp + 12);
      float xs[16] = {x0.x, x0.y, x0.z, x0.w, x1.x, x1.y, x1.z, x1.w,
                      x2.x, x2.y, x2.z, x2.w, x3.x, x3.y, x3.z, x3.w};
#pragma unroll
      for (int r = 0; r < 16; ++r) a[r] = fmaf(xs[r], w, a[r]);
    }
#pragma unroll
    for (int r = 0; r < 16; ++r) x1t[col * 36 + r0 + r] = silu_f(a[r]);
  }
  __syncthreads();

  // L2: 128 -> 128
  {
    int col = t & 127, r0 = (t >> 7) * 16;
    float a[16];
    float bb = bo2[col];
#pragma unroll
    for (int r = 0; r < 16; ++r) a[r] = bb;
    for (int k = 0; k < 128; ++k) {
      float w = wo2[k * 128 + col];
      const float* xp = &x1t[k * 36 + r0];
      float4 x0 = *(const float4*)(xp + 0);
      float4 x1 = *(const float4*)(xp + 4);
      float4 x2 = *(const float4*)(xp + 8);
      float4 x3 = *(const float4*)(xp + 12);
      float xs[16] = {x0.x, x0.y, x0.z, x0.w, x1.x, x1.y, x1.z, x1.w,
                      x2.x, x2.y, x2.z, x2.w, x3.x, x3.y, x3.z, x3.w};
#pragma unroll
      for (int r = 0; r < 16; ++r) a[r] = fmaf(xs[r], w, a[r]);
    }
#pragma unroll
    for (int r = 0; r < 16; ++r) x2t[col * 36 + r0 + r] = silu_f(a[r]);
  }
  __syncthreads();

  // L3: 128 -> 256, thread = col, all 32 rows in registers
  {
    int col = t;
    float a[32];
    float bb = bo3[col];
#pragma unroll
    for (int r = 0; r < 32; ++r) a[r] = bb;
    for (int k = 0; k < 128; ++k) {
      float w = wo3[k * 256 + col];
      const float* xp = &x2t[k * 36];
#pragma unroll
      for (int q = 0; q < 8; ++q) {
        float4 xv = *(const float4*)(xp + q * 4);
        a[q * 4 + 0] = fmaf(xv.x, w, a[q * 4 + 0]);
        a[q * 4 + 1] = fmaf(xv.y, w, a[q * 4 + 1]);
        a[q * 4 + 2] = fmaf(xv.z, w, a[q * 4 + 2]);
        a[q * 4 + 3] = fmaf(xv.w, w, a[q * 4 + 3]);
      }
    }
    float* op = out + ((size_t)(b * 512 + e0)) * 256 + col;
#pragma unroll
    for (int r = 0; r < 32; ++r) op[(size_t)r * 256] = a[r];
  }
}

extern "C" void kernel_launch(void* const* d_in, const int* in_sizes, int n_in,
                              void* d_out, int out_size, void* d_ws, size_t ws_size,
                              hipStream_t stream) {
  const float* h        = (const float*)d_in[0];
  const float* h_full   = (const float*)d_in[1];
  const int*   z        = (const int*)d_in[2];
  const float* e_feat   = (const float*)d_in[4];
  const int*   abs_idx  = (const int*)d_in[5];
  const int*   att_dst  = (const int*)d_in[6];
  const float* att_dist = (const float*)d_in[7];
  const float* att_vec  = (const float*)d_in[8];
  const float* w_zemb   = (const float*)d_in[9];
  const float* w1_rad   = (const float*)d_in[10];
  const float* b1_rad   = (const float*)d_in[11];
  const float* w2_rad   = (const float*)d_in[12];
  const float* b2_rad   = (const float*)d_in[13];
  const float* wg1      = (const float*)d_in[14];
  const float* bg1      = (const float*)d_in[15];
  const float* wg2      = (const float*)d_in[16];
  const float* bg2      = (const float*)d_in[17];
  const float* we1      = (const float*)d_in[18];
  const float* be1      = (const float*)d_in[19];
  const float* we2      = (const float*)d_in[20];
  const float* be2      = (const float*)d_in[21];
  const float* wo1      = (const float*)d_in[22];
  const float* bo1      = (const float*)d_in[23];
  const float* wo2      = (const float*)d_in[24];
  const float* bo2      = (const float*)d_in[25];
  const float* wo3      = (const float*)d_in[26];
  const float* bo3      = (const float*)d_in[27];
  float* out = (float*)d_out;

  // workspace layout (~7.1 MB)
  float* a_glob    = (float*)d_ws;                      // MAXACT*128
  float* coef_glob = a_glob + MAXACT * 128;             // MAXACT*192
  float* acc_glob  = coef_glob + MAXACT * 192;          // MAXACT*96
  float* meta_f    = acc_glob + (size_t)MAXACT * ACCW;  // MAXACT*4
  float* vabs      = meta_f + MAXACT * 4;               // 64*80
  float* sfull     = vabs + NB * OD_;                   // 512*80
  int* widx   = (int*)(sfull + NE_ * OD_);              // 8192
  int* active = widx + FLAT;                            // 4096
  int* meta_b = active + MAXACT;                        // 4096
  int* count  = meta_b + MAXACT;                        // 1

  k_init<<<1536, 256, 0, stream>>>(acc_glob, vabs, widx, count);
  k_scatter<<<16, 256, 0, stream>>>(att_dst, widx);
  k_build<<<32, 256, 0, stream>>>(widx, active, count);
  k_node<<<MAXACT, 128, 0, stream>>>(count, active, widx, att_dist, att_vec, z, w_zemb,
                                     abs_idx, w1_rad, b1_rad, h, wg1, bg1, wg2, bg2,
                                     h_full, a_glob, coef_glob, meta_f, meta_b);
  k_rgemm<<<dim3(36, 64), 256, 0, stream>>>(count, a_glob, coef_glob, w2_rad, b2_rad,
                                            acc_glob);
  k_combine<<<1536, 256, 0, stream>>>(count, acc_glob, meta_f, meta_b, vabs);
  k_scales<<<512, 128, 0, stream>>>(e_feat, we1, be1, we2, be2, sfull);
  k_head<<<1024, 256, 0, stream>>>(vabs, sfull, wo1, bo1, wo2, bo2, wo3, bo3, out);
}

// Round 8
// 310.162 us; speedup vs baseline: 4.2159x; 1.0204x over previous
//
#include <hip/hip_runtime.h>
#include <math.h>

#define FLAT   8192
#define NB     64
#define OD_    80
#define NE_    512
#define EATT_  4096
#define MAXACT 4096
// acc_glob: 96 floats/node, atomically accumulated by k_rgemm:
//   [0..31]  out_s partial (pre gate/env/norm)
//   [32..47] q (scalar coeff that multiplies yv)
//   [48..95] D-term out_v, layout comp*16 + o
#define ACCW 96

__device__ __forceinline__ float silu_f(float x) { return x / (1.f + __expf(-x)); }
__device__ __forceinline__ float sigm_f(float x) { return 1.f / (1.f + __expf(-x)); }

// ---------------- init: zero acc + vabs, widx=-1, count=0 ----------------
__global__ void k_init(float* acc, float* vabs, int* widx, int* count) {
  int t = blockIdx.x * 256 + threadIdx.x;
  if (t < MAXACT * ACCW) acc[t] = 0.f;
  if (t < FLAT) widx[t] = -1;
  if (t < NB * OD_) vabs[t] = 0.f;
  if (t == 0) *count = 0;
}

// ---------------- scatter: last-write-wins == max edge index ----------------
__global__ void k_scatter(const int* __restrict__ att_dst, int* widx) {
  int i = blockIdx.x * 256 + threadIdx.x;
  if (i < EATT_) atomicMax(&widx[att_dst[i]], i);
}

// ---------------- compact active-node list ----------------
__global__ void k_build(const int* __restrict__ widx, int* active, int* count) {
  int j = blockIdx.x * 256 + threadIdx.x;
  if (j < FLAT && widx[j] >= 0) {
    int p = atomicAdd(count, 1);
    active[p] = j;
  }
}

// ---------------- per-batch absorber row of gate layer 1: h_abs @ wg1 ----------------
__global__ void k_gabs(const int* __restrict__ abs_idx, const float* __restrict__ h,
                       const float* __restrict__ wg1, float* habs_g) {
  int b = blockIdx.x;   // 64
  int t = threadIdx.x;  // 128
  __shared__ float hs[128];
  int nabs = abs_idx[b];
  hs[t] = h[(size_t)(b * 128 + nabs) * 128 + t];
  __syncthreads();
  float g = 0.f;
  for (int c = 0; c < 128; ++c) g = fmaf(hs[c], wg1[c * 128 + t], g);
  habs_g[b * 128 + t] = g;
}

// ---------------- per active node: rbf, hidden a(128), gate, env, coefs ----------------
__global__ void k_node(const int* __restrict__ count, const int* __restrict__ active,
                       const int* __restrict__ widx,
                       const float* __restrict__ att_dist, const float* __restrict__ att_vec,
                       const int* __restrict__ z, const float* __restrict__ w_zemb,
                       const int* __restrict__ abs_idx,
                       const float* __restrict__ w1_rad, const float* __restrict__ b1_rad,
                       const float* __restrict__ h, const float* __restrict__ habs_g,
                       const float* __restrict__ wg1, const float* __restrict__ bg1,
                       const float* __restrict__ wg2, const float* __restrict__ bg2,
                       const float* __restrict__ h_full,
                       float* a_glob, float* coef_glob, float* meta_f, int* meta_b) {
  int pos = blockIdx.x;
  if (pos >= *count) return;
  int t = threadIdx.x;  // 128 threads
  __shared__ float win[49];
  __shared__ float yv_s[3];
  __shared__ float red[128];
  __shared__ float sh_d;

  int j = active[pos];
  int b = j >> 7;
  int n = j & 127;
  int e = widx[j];

  if (t == 0) {
    float d = att_dist[e];
    sh_d = d;
    float eps = fmaxf(d, 1e-8f);
    const float s3 = 1.7320508075688772f;
    yv_s[0] = s3 * att_vec[e * 3 + 0] / eps;
    yv_s[1] = s3 * att_vec[e * 3 + 1] / eps;
    yv_s[2] = s3 * att_vec[e * 3 + 2] / eps;
  }
  int nabs = abs_idx[b];
  float isab = (n == nabs) ? 1.f : 0.f;
  if (t < 32) win[t] = w_zemb[z[j] * 32 + t];
  if (t == 32) win[32] = isab;
  if (t >= 33 && t < 49) {
    int k = t - 33;
    float d = att_dist[e];
    float x = (d - (float)k * (1.f / 3.f)) * 3.f;  // width = CUTOFF/(RBF-1) = 1/3
    win[t] = __expf(-0.5f * x * x);
  }
  __syncthreads();

  // hidden a = silu(win @ w1_rad + b1_rad)   (49 -> 128)
  {
    float s = b1_rad[t];
    for (int k = 0; k < 49; ++k) s = fmaf(win[k], w1_rad[k * 128 + t], s);
    a_glob[pos * 128 + t] = silu_f(s);
  }

  // gate MLP hidden (273 -> 128); h_abs part precomputed per-batch (k_gabs)
  {
    float g = bg1[t] + habs_g[b * 128 + t];
    const float* hn = h + (size_t)j * 128;
    for (int c = 0; c < 128; ++c) g = fmaf(hn[c], wg1[(128 + c) * 128 + t], g);
    for (int k = 0; k < 16; ++k)  g = fmaf(win[33 + k], wg1[(256 + k) * 128 + t], g);
    g = fmaf(isab, wg1[272 * 128 + t], g);
    red[t] = silu_f(g) * wg2[t];
  }
  __syncthreads();

  // per-node contraction coefficients: [s1(64), p*inv_s3(32), v1(96)]
  const float* hf = h_full + (size_t)j * 160;
  if (t < 64) coef_glob[pos * 192 + t] = hf[t];
  if (t >= 64 && t < 96) {
    int i = t - 64;
    float pv = hf[64 + i * 3 + 0] * yv_s[0] + hf[64 + i * 3 + 1] * yv_s[1] +
               hf[64 + i * 3 + 2] * yv_s[2];
    coef_glob[pos * 192 + t] = pv * 0.5773502691896258f;
  }
  if (t < 96) coef_glob[pos * 192 + 96 + t] = hf[64 + t];

  if (t == 0) {
    float tot = 0.f;
    for (int k = 0; k < 128; ++k) tot += red[k];
    tot += bg2[0];
    float gate = sigm_f(tot);
    float d = sh_d;
    float env = (d < 5.f) ? 0.5f * (__cosf(3.14159265358979323846f * d * 0.2f) + 1.f) : 0.f;
    meta_f[pos * 4 + 0] = yv_s[0];
    meta_f[pos * 4 + 1] = yv_s[1];
    meta_f[pos * 4 + 2] = yv_s[2];
    meta_f[pos * 4 + 3] = gate * env;
    meta_b[pos] = b;
  }
}

// ---------------- radial GEMM + fused contraction (R7-proven, unchanged) ----------------
__global__ __launch_bounds__(256) void k_rgemm(const int* __restrict__ count,
                                               const float* __restrict__ a_glob,
                                               const float* __restrict__ coef_glob,
                                               const float* __restrict__ w2,
                                               const float* __restrict__ b2,
                                               float* __restrict__ acc_glob) {
  int cc = blockIdx.x;         // 0..35 (col chunk of 128)
  int nbase = blockIdx.y * 64;
  if (nbase >= *count) return;
  int t = threadIdx.x;
  int tx = t & 15, ty = t >> 4;
  int n0 = ty * 4;

  __shared__ float w_s[2][16][128];  // 16 KB
  __shared__ float a_s[2][16][64];   // 8 KB (transposed [k][node])

  const float* wbase = w2 + cc * 128;
  int wr = t >> 5;             // 0..7; rows wr and wr+8
  int wc4 = t & 31;            // col/4
  int anode = t >> 2, aq = t & 3;
  const float* aptr = a_glob + (size_t)(nbase + anode) * 128 + aq * 4;

  float4 wpre0, wpre1, apre;
  wpre0 = *(const float4*)(wbase + (size_t)wr * 4608 + wc4 * 4);
  wpre1 = *(const float4*)(wbase + (size_t)(wr + 8) * 4608 + wc4 * 4);
  apre  = *(const float4*)aptr;
  *(float4*)&w_s[0][wr][wc4 * 4]     = wpre0;
  *(float4*)&w_s[0][wr + 8][wc4 * 4] = wpre1;
  a_s[0][aq * 4 + 0][anode] = apre.x;
  a_s[0][aq * 4 + 1][anode] = apre.y;
  a_s[0][aq * 4 + 2][anode] = apre.z;
  a_s[0][aq * 4 + 3][anode] = apre.w;
  __syncthreads();

  float acc[4][8];
#pragma unroll
  for (int i = 0; i < 4; ++i)
#pragma unroll
    for (int j = 0; j < 8; ++j) acc[i][j] = 0.f;

  for (int kb = 0; kb < 8; ++kb) {
    int cur = kb & 1;
    if (kb < 7) {
      wpre0 = *(const float4*)(wbase + (size_t)((kb + 1) * 16 + wr) * 4608 + wc4 * 4);
      wpre1 = *(const float4*)(wbase + (size_t)((kb + 1) * 16 + wr + 8) * 4608 + wc4 * 4);
      apre  = *(const float4*)(aptr + (kb + 1) * 16);
    }
#pragma unroll
    for (int k = 0; k < 16; ++k) {
      float4 av  = *(const float4*)&a_s[cur][k][n0];
      float4 w0  = *(const float4*)&w_s[cur][k][tx * 4];
      float4 w1v = *(const float4*)&w_s[cur][k][64 + tx * 4];
#pragma unroll
      for (int i = 0; i < 4; ++i) {
        float a = (i == 0) ? av.x : (i == 1) ? av.y : (i == 2) ? av.z : av.w;
        acc[i][0] = fmaf(a, w0.x,  acc[i][0]);
        acc[i][1] = fmaf(a, w0.y,  acc[i][1]);
        acc[i][2] = fmaf(a, w0.z,  acc[i][2]);
        acc[i][3] = fmaf(a, w0.w,  acc[i][3]);
        acc[i][4] = fmaf(a, w1v.x, acc[i][4]);
        acc[i][5] = fmaf(a, w1v.y, acc[i][5]);
        acc[i][6] = fmaf(a, w1v.z, acc[i][6]);
        acc[i][7] = fmaf(a, w1v.w, acc[i][7]);
      }
    }
    if (kb < 7) {
      int nxt = cur ^ 1;
      *(float4*)&w_s[nxt][wr][wc4 * 4]     = wpre0;
      *(float4*)&w_s[nxt][wr + 8][wc4 * 4] = wpre1;
      a_s[nxt][aq * 4 + 0][anode] = apre.x;
      a_s[nxt][aq * 4 + 1][anode] = apre.y;
      a_s[nxt][aq * 4 + 2][anode] = apre.z;
      a_s[nxt][aq * 4 + 3][anode] = apre.w;
    }
    __syncthreads();
  }

  {
    const float* bp = b2 + cc * 128 + tx * 4;
    float4 bq0 = *(const float4*)(bp + 0);
    float4 bq1 = *(const float4*)(bp + 64);
#pragma unroll
    for (int i = 0; i < 4; ++i) {
      acc[i][0] += bq0.x; acc[i][1] += bq0.y; acc[i][2] += bq0.z; acc[i][3] += bq0.w;
      acc[i][4] += bq1.x; acc[i][5] += bq1.y; acc[i][6] += bq1.z; acc[i][7] += bq1.w;
    }
  }

  if (cc < 24) {
    int txh = tx >> 3;
#pragma unroll
    for (int i = 0; i < 4; ++i) {
      const float* cfp = coef_glob + (size_t)(nbase + n0 + i) * 192 + cc * 4 + txh;
      float cf0 = cfp[0];
      float cf1 = cfp[2];
      float* dst = acc_glob + (size_t)(nbase + n0 + i) * ACCW + (tx & 7) * 4;
#pragma unroll
      for (int e = 0; e < 4; ++e) {
        float v = acc[i][e] * cf0 + acc[i][4 + e] * cf1;
        v += __shfl_xor(v, 8);
        if (tx < 8) atomicAdd(&dst[e], v);
      }
    }
  } else if (cc < 32) {
    int txq = tx >> 2;
#pragma unroll
    for (int i = 0; i < 4; ++i) {
      const float* cfp = coef_glob + (size_t)(nbase + n0 + i) * 192 + (cc - 24) * 8 + txq;
      float cf0 = cfp[0];
      float cf1 = cfp[4];
      float* dst = acc_glob + (size_t)(nbase + n0 + i) * ACCW + 32 + (tx & 3) * 4;
#pragma unroll
      for (int e = 0; e < 4; ++e) {
        float v = acc[i][e] * cf0 + acc[i][4 + e] * cf1;
        v += __shfl_xor(v, 4);
        v += __shfl_xor(v, 8);
        if (tx < 4) atomicAdd(&dst[e], v);
      }
    }
  } else {
    int txq = tx >> 2;
#pragma unroll
    for (int i = 0; i < 4; ++i) {
      const float* cfp = coef_glob + (size_t)(nbase + n0 + i) * 192 + 96 +
                         ((cc - 32) * 8 + txq) * 3;
      float* dstb = acc_glob + (size_t)(nbase + n0 + i) * ACCW + 48 + (tx & 3) * 4;
#pragma unroll
      for (int comp = 0; comp < 3; ++comp) {
        float cf0 = cfp[comp];
        float cf1 = cfp[12 + comp];
#pragma unroll
        for (int e = 0; e < 4; ++e) {
          float v = acc[i][e] * cf0 + acc[i][4 + e] * cf1;
          v += __shfl_xor(v, 4);
          v += __shfl_xor(v, 8);
          if (tx < 4) atomicAdd(&dstb[comp * 16 + e], v);
        }
      }
    }
  }
}

// ---------------- combine 96 slots/node -> v_abs[b][80] ----------------
__global__ void k_combine(const int* __restrict__ count, const float* __restrict__ acc_glob,
                          const float* __restrict__ meta_f, const int* __restrict__ meta_b,
                          float* vabs) {
  int g = blockIdx.x * 256 + threadIdx.x;
  int pos = g / ACCW, slot = g - pos * ACCW;
  if (pos >= *count) return;
  const float* acc = acc_glob + (size_t)pos * ACCW;
  float sc = meta_f[pos * 4 + 3] * 0.10206207261596577f;  // gate*env / sqrt(96)
  float* vb = vabs + meta_b[pos] * 80;
  if (slot < 32) {
    atomicAdd(&vb[slot], acc[slot] * sc);
  } else if (slot < 48) {
    int o = slot - 32;
    float q = acc[slot] * sc;
    atomicAdd(&vb[32 + o * 3 + 0], q * meta_f[pos * 4 + 0]);
    atomicAdd(&vb[32 + o * 3 + 1], q * meta_f[pos * 4 + 1]);
    atomicAdd(&vb[32 + o * 3 + 2], q * meta_f[pos * 4 + 2]);
  } else {
    int s2 = slot - 48;          // comp*16 + o
    int comp = s2 >> 4, o = s2 & 15;
    atomicAdd(&vb[32 + o * 3 + comp], acc[slot] * sc);
  }
}

// ---------------- edge-feature scales -> scale_full[512][80] ----------------
__global__ void k_scales(const float* __restrict__ e_feat,
                         const float* __restrict__ we1, const float* __restrict__ be1,
                         const float* __restrict__ we2, const float* __restrict__ be2,
                         float* sfull) {
  int row = blockIdx.x;  // 512
  int t = threadIdx.x;   // 128
  __shared__ float hid[128];
  const float* ef = e_feat + row * 16;
  float s = be1[t];
  for (int k = 0; k < 16; ++k) s = fmaf(ef[k], we1[k * 128 + t], s);
  hid[t] = silu_f(s);
  __syncthreads();
  if (t < 48) {
    float o = be2[t];
    for (int k = 0; k < 128; ++k) o = fmaf(hid[k], we2[k * 48 + t], o);
    if (t < 32) sfull[row * 80 + t] = o;
    else {
      int oo = t - 32;
      sfull[row * 80 + 32 + oo * 3 + 0] = o;
      sfull[row * 80 + 32 + oo * 3 + 1] = o;
      sfull[row * 80 + 32 + oo * 3 + 2] = o;
    }
  }
}

// ---------------- head G1: build inv + (32768x48)@wo1 + silu -> xg ----------------
// Block: 64 rows x 128 cols, K=48 (single LDS tile; w1 24 KB + invt 12 KB).
__global__ __launch_bounds__(256) void k_hg1(const float* __restrict__ vabs,
                                             const float* __restrict__ sfull,
                                             const float* __restrict__ wo1,
                                             const float* __restrict__ bo1,
                                             float* __restrict__ xg) {
  int rbase = blockIdx.x * 64;   // 512 blocks
  int b = rbase >> 9;
  int e0 = rbase & 511;
  int t = threadIdx.x;
  int tx = t & 15, ty = t >> 4;
  int n0 = ty * 4;

  __shared__ float w_s[48 * 128];   // [k][col], 24 KB
  __shared__ float invt[48][64];    // [k][row], 12 KB
  __shared__ float va[80];

  if (t < 80) va[t] = vabs[b * 80 + t];
  {
    const float4* wg = (const float4*)wo1;
    float4* ws4 = (float4*)w_s;
#pragma unroll
    for (int it = 0; it < 6; ++it) ws4[t + it * 256] = wg[t + it * 256];
  }
  __syncthreads();

  // inv transposed [c][row]: 48*64 elems, 12 per thread
  for (int idx = t; idx < 48 * 64; idx += 256) {
    int cd = idx >> 6, r = idx & 63;
    const float* sf = sfull + (size_t)(e0 + r) * 80;
    float v;
    if (cd < 32) v = va[cd] * sf[cd];
    else {
      int base = 32 + (cd - 32) * 3;
      float m0 = va[base + 0] * sf[base + 0];
      float m1 = va[base + 1] * sf[base + 1];
      float m2 = va[base + 2] * sf[base + 2];
      v = sqrtf(m0 * m0 + m1 * m1 + m2 * m2 + 1e-12f);
    }
    invt[cd][r] = v;
  }
  __syncthreads();

  float acc[4][8];
#pragma unroll
  for (int i = 0; i < 4; ++i)
#pragma unroll
    for (int j = 0; j < 8; ++j) acc[i][j] = 0.f;

  for (int k = 0; k < 48; ++k) {
    float4 av  = *(const float4*)&invt[k][n0];
    float4 w0  = *(const float4*)&w_s[k * 128 + tx * 4];
    float4 w1v = *(const float4*)&w_s[k * 128 + 64 + tx * 4];
#pragma unroll
    for (int i = 0; i < 4; ++i) {
      float a = (i == 0) ? av.x : (i == 1) ? av.y : (i == 2) ? av.z : av.w;
      acc[i][0] = fmaf(a, w0.x,  acc[i][0]);
      acc[i][1] = fmaf(a, w0.y,  acc[i][1]);
      acc[i][2] = fmaf(a, w0.z,  acc[i][2]);
      acc[i][3] = fmaf(a, w0.w,  acc[i][3]);
      acc[i][4] = fmaf(a, w1v.x, acc[i][4]);
      acc[i][5] = fmaf(a, w1v.y, acc[i][5]);
      acc[i][6] = fmaf(a, w1v.z, acc[i][6]);
      acc[i][7] = fmaf(a, w1v.w, acc[i][7]);
    }
  }

  float4 bq0 = *(const float4*)(bo1 + tx * 4);
  float4 bq1 = *(const float4*)(bo1 + 64 + tx * 4);
#pragma unroll
  for (int i = 0; i < 4; ++i) {
    float* dst = xg + (size_t)(rbase + n0 + i) * 128 + tx * 4;
    *(float4*)dst = make_float4(silu_f(acc[i][0] + bq0.x), silu_f(acc[i][1] + bq0.y),
                                silu_f(acc[i][2] + bq0.z), silu_f(acc[i][3] + bq0.w));
    *(float4*)(dst + 64) = make_float4(silu_f(acc[i][4] + bq1.x), silu_f(acc[i][5] + bq1.y),
                                       silu_f(acc[i][6] + bq1.z), silu_f(acc[i][7] + bq1.w));
  }
}

// ---------------- head G2: (32768x128)@wo2 + silu, IN-PLACE on xg ----------------
// Each block reads only its own 64 rows (fully consumed before epilogue) then
// overwrites them — safe in-place. R7 k_rgemm skeleton.
__global__ __launch_bounds__(256) void k_hg2(const float* __restrict__ wo2,
                                             const float* __restrict__ bo2,
                                             float* __restrict__ xg) {
  int rbase = blockIdx.x * 64;   // 512 blocks
  int t = threadIdx.x;
  int tx = t & 15, ty = t >> 4;
  int n0 = ty * 4;

  __shared__ float w_s[2][16][128];
  __shared__ float a_s[2][16][64];

  int wr = t >> 5, wc4 = t & 31;
  int anode = t >> 2, aq = t & 3;
  const float* aptr = xg + (size_t)(rbase + anode) * 128 + aq * 4;

  float4 wpre0, wpre1, apre;
  wpre0 = *(const float4*)(wo2 + (size_t)wr * 128 + wc4 * 4);
  wpre1 = *(const float4*)(wo2 + (size_t)(wr + 8) * 128 + wc4 * 4);
  apre  = *(const float4*)aptr;
  *(float4*)&w_s[0][wr][wc4 * 4]     = wpre0;
  *(float4*)&w_s[0][wr + 8][wc4 * 4] = wpre1;
  a_s[0][aq * 4 + 0][anode] = apre.x;
  a_s[0][aq * 4 + 1][anode] = apre.y;
  a_s[0][aq * 4 + 2][anode] = apre.z;
  a_s[0][aq * 4 + 3][anode] = apre.w;
  __syncthreads();

  float acc[4][8];
#pragma unroll
  for (int i = 0; i < 4; ++i)
#pragma unroll
    for (int j = 0; j < 8; ++j) acc[i][j] = 0.f;

  for (int kb = 0; kb < 8; ++kb) {
    int cur = kb & 1;
    if (kb < 7) {
      wpre0 = *(const float4*)(wo2 + (size_t)((kb + 1) * 16 + wr) * 128 + wc4 * 4);
      wpre1 = *(const float4*)(wo2 + (size_t)((kb + 1) * 16 + wr + 8) * 128 + wc4 * 4);
      apre  = *(const float4*)(aptr + (kb + 1) * 16);
    }
#pragma unroll
    for (int k = 0; k < 16; ++k) {
      float4 av  = *(const float4*)&a_s[cur][k][n0];
      float4 w0  = *(const float4*)&w_s[cur][k][tx * 4];
      float4 w1v = *(const float4*)&w_s[cur][k][64 + tx * 4];
#pragma unroll
      for (int i = 0; i < 4; ++i) {
        float a = (i == 0) ? av.x : (i == 1) ? av.y : (i == 2) ? av.z : av.w;
        acc[i][0] = fmaf(a, w0.x,  acc[i][0]);
        acc[i][1] = fmaf(a, w0.y,  acc[i][1]);
        acc[i][2] = fmaf(a, w0.z,  acc[i][2]);
        acc[i][3] = fmaf(a, w0.w,  acc[i][3]);
        acc[i][4] = fmaf(a, w1v.x, acc[i][4]);
        acc[i][5] = fmaf(a, w1v.y, acc[i][5]);
        acc[i][6] = fmaf(a, w1v.z, acc[i][6]);
        acc[i][7] = fmaf(a, w1v.w, acc[i][7]);
      }
    }
    if (kb < 7) {
      int nxt = cur ^ 1;
      *(float4*)&w_s[nxt][wr][wc4 * 4]     = wpre0;
      *(float4*)&w_s[nxt][wr + 8][wc4 * 4] = wpre1;
      a_s[nxt][aq * 4 + 0][anode] = apre.x;
      a_s[nxt][aq * 4 + 1][anode] = apre.y;
      a_s[nxt][aq * 4 + 2][anode] = apre.z;
      a_s[nxt][aq * 4 + 3][anode] = apre.w;
    }
    __syncthreads();
  }

  float4 bq0 = *(const float4*)(bo2 + tx * 4);
  float4 bq1 = *(const float4*)(bo2 + 64 + tx * 4);
#pragma unroll
  for (int i = 0; i < 4; ++i) {
    float* dst = xg + (size_t)(rbase + n0 + i) * 128 + tx * 4;
    *(float4*)dst = make_float4(silu_f(acc[i][0] + bq0.x), silu_f(acc[i][1] + bq0.y),
                                silu_f(acc[i][2] + bq0.z), silu_f(acc[i][3] + bq0.w));
    *(float4*)(dst + 64) = make_float4(silu_f(acc[i][4] + bq1.x), silu_f(acc[i][5] + bq1.y),
                                       silu_f(acc[i][6] + bq1.z), silu_f(acc[i][7] + bq1.w));
  }
}

// ---------------- head G3: (32768x128)@wo3 + bo3 -> out ----------------
__global__ __launch_bounds__(256) void k_hg3(const float* __restrict__ xg,
                                             const float* __restrict__ wo3,
                                             const float* __restrict__ bo3,
                                             float* __restrict__ out) {
  int cc = blockIdx.x;            // 0..1 (col chunk of 128)
  int rbase = blockIdx.y * 64;    // 512
  int t = threadIdx.x;
  int tx = t & 15, ty = t >> 4;
  int n0 = ty * 4;

  __shared__ float w_s[2][16][128];
  __shared__ float a_s[2][16][64];

  const float* wbase = wo3 + cc * 128;
  int wr = t >> 5, wc4 = t & 31;
  int anode = t >> 2, aq = t & 3;
  const float* aptr = xg + (size_t)(rbase + anode) * 128 + aq * 4;

  float4 wpre0, wpre1, apre;
  wpre0 = *(const float4*)(wbase + (size_t)wr * 256 + wc4 * 4);
  wpre1 = *(const float4*)(wbase + (size_t)(wr + 8) * 256 + wc4 * 4);
  apre  = *(const float4*)aptr;
  *(float4*)&w_s[0][wr][wc4 * 4]     = wpre0;
  *(float4*)&w_s[0][wr + 8][wc4 * 4] = wpre1;
  a_s[0][aq * 4 + 0][anode] = apre.x;
  a_s[0][aq * 4 + 1][anode] = apre.y;
  a_s[0][aq * 4 + 2][anode] = apre.z;
  a_s[0][aq * 4 + 3][anode] = apre.w;
  __syncthreads();

  float acc[4][8];
#pragma unroll
  for (int i = 0; i < 4; ++i)
#pragma unroll
    for (int j = 0; j < 8; ++j) acc[i][j] = 0.f;

  for (int kb = 0; kb < 8; ++kb) {
    int cur = kb & 1;
    if (kb < 7) {
      wpre0 = *(const float4*)(wbase + (size_t)((kb + 1) * 16 + wr) * 256 + wc4 * 4);
      wpre1 = *(const float4*)(wbase + (size_t)((kb + 1) * 16 + wr + 8) * 256 + wc4 * 4);
      apre  = *(const float4*)(aptr + (kb + 1) * 16);
    }
#pragma unroll
    for (int k = 0; k < 16; ++k) {
      float4 av  = *(const float4*)&a_s[cur][k][n0];
      float4 w0  = *(const float4*)&w_s[cur][k][tx * 4];
      float4 w1v = *(const float4*)&w_s[cur][k][64 + tx * 4];
#pragma unroll
      for (int i = 0; i < 4; ++i) {
        float a = (i == 0) ? av.x : (i == 1) ? av.y : (i == 2) ? av.z : av.w;
        acc[i][0] = fmaf(a, w0.x,  acc[i][0]);
        acc[i][1] = fmaf(a, w0.y,  acc[i][1]);
        acc[i][2] = fmaf(a, w0.z,  acc[i][2]);
        acc[i][3] = fmaf(a, w0.w,  acc[i][3]);
        acc[i][4] = fmaf(a, w1v.x, acc[i][4]);
        acc[i][5] = fmaf(a, w1v.y, acc[i][5]);
        acc[i][6] = fmaf(a, w1v.z, acc[i][6]);
        acc[i][7] = fmaf(a, w1v.w, acc[i][7]);
      }
    }
    if (kb < 7) {
      int nxt = cur ^ 1;
      *(float4*)&w_s[nxt][wr][wc4 * 4]     = wpre0;
      *(float4*)&w_s[nxt][wr + 8][wc4 * 4] = wpre1;
      a_s[nxt][aq * 4 + 0][anode] = apre.x;
      a_s[nxt][aq * 4 + 1][anode] = apre.y;
      a_s[nxt][aq * 4 + 2][anode] = apre.z;
      a_s[nxt][aq * 4 + 3][anode] = apre.w;
    }
    __syncthreads();
  }

  const float* bp = bo3 + cc * 128 + tx * 4;
  float4 bq0 = *(const float4*)(bp + 0);
  float4 bq1 = *(const float4*)(bp + 64);
#pragma unroll
  for (int i = 0; i < 4; ++i) {
    float* dst = out + (size_t)(rbase + n0 + i) * 256 + cc * 128 + tx * 4;
    *(float4*)dst = make_float4(acc[i][0] + bq0.x, acc[i][1] + bq0.y,
                                acc[i][2] + bq0.z, acc[i][3] + bq0.w);
    *(float4*)(dst + 64) = make_float4(acc[i][4] + bq1.x, acc[i][5] + bq1.y,
                                       acc[i][6] + bq1.z, acc[i][7] + bq1.w);
  }
}

extern "C" void kernel_launch(void* const* d_in, const int* in_sizes, int n_in,
                              void* d_out, int out_size, void* d_ws, size_t ws_size,
                              hipStream_t stream) {
  const float* h        = (const float*)d_in[0];
  const float* h_full   = (const float*)d_in[1];
  const int*   z        = (const int*)d_in[2];
  const float* e_feat   = (const float*)d_in[4];
  const int*   abs_idx  = (const int*)d_in[5];
  const int*   att_dst  = (const int*)d_in[6];
  const float* att_dist = (const float*)d_in[7];
  const float* att_vec  = (const float*)d_in[8];
  const float* w_zemb   = (const float*)d_in[9];
  const float* w1_rad   = (const float*)d_in[10];
  const float* b1_rad   = (const float*)d_in[11];
  const float* w2_rad   = (const float*)d_in[12];
  const float* b2_rad   = (const float*)d_in[13];
  const float* wg1      = (const float*)d_in[14];
  const float* bg1      = (const float*)d_in[15];
  const float* wg2      = (const float*)d_in[16];
  const float* bg2      = (const float*)d_in[17];
  const float* we1      = (const float*)d_in[18];
  const float* be1      = (const float*)d_in[19];
  const float* we2      = (const float*)d_in[20];
  const float* be2      = (const float*)d_in[21];
  const float* wo1      = (const float*)d_in[22];
  const float* bo1      = (const float*)d_in[23];
  const float* wo2      = (const float*)d_in[24];
  const float* bo2      = (const float*)d_in[25];
  const float* wo3      = (const float*)d_in[26];
  const float* bo3      = (const float*)d_in[27];
  float* out = (float*)d_out;

  // workspace layout (~17.2 MB): persistent small buffers first, then a
  // region where phase-1 (a/coef/acc, 6.8 MB) and phase-2 (xg, 16.8 MB) alias.
  float* meta_f  = (float*)d_ws;                 // MAXACT*4
  float* vabs    = meta_f + MAXACT * 4;          // 64*80
  float* sfull   = vabs + NB * OD_;              // 512*80
  float* habs_g  = sfull + NE_ * OD_;            // 64*128
  int* widx   = (int*)(habs_g + NB * 128);       // 8192
  int* active = widx + FLAT;                     // 4096
  int* meta_b = active + MAXACT;                 // 4096
  int* count  = meta_b + MAXACT;                 // 1 (+pad to 16B)
  float* big  = (float*)(count + 15);            // aligned big region
  float* a_glob    = big;                        // MAXACT*128   (phase 1)
  float* coef_glob = a_glob + MAXACT * 128;      // MAXACT*192   (phase 1)
  float* acc_glob  = coef_glob + MAXACT * 192;   // MAXACT*96    (phase 1)
  float* xg        = big;                        // 32768*128    (phase 2, aliases phase 1)

  k_init<<<1536, 256, 0, stream>>>(acc_glob, vabs, widx, count);
  k_scatter<<<16, 256, 0, stream>>>(att_dst, widx);
  k_build<<<32, 256, 0, stream>>>(widx, active, count);
  k_gabs<<<NB, 128, 0, stream>>>(abs_idx, h, wg1, habs_g);
  k_node<<<MAXACT, 128, 0, stream>>>(count, active, widx, att_dist, att_vec, z, w_zemb,
                                     abs_idx, w1_rad, b1_rad, h, habs_g, wg1, bg1, wg2, bg2,
                                     h_full, a_glob, coef_glob, meta_f, meta_b);
  k_rgemm<<<dim3(36, 64), 256, 0, stream>>>(count, a_glob, coef_glob, w2_rad, b2_rad,
                                            acc_glob);
  k_combine<<<1536, 256, 0, stream>>>(count, acc_glob, meta_f, meta_b, vabs);
  k_scales<<<512, 128, 0, stream>>>(e_feat, we1, be1, we2, be2, sfull);
  k_hg1<<<512, 256, 0, stream>>>(vabs, sfull, wo1, bo1, xg);
  k_hg2<<<512, 256, 0, stream>>>(wo2, bo2, xg);
  k_hg3<<<dim3(2, 512), 256, 0, stream>>>(xg, wo3, bo3, out);
}